// Round 17
// baseline (74.770 us; speedup 1.0000x reference)
//
#include <hip/hip_runtime.h>
#include <hip/hip_bf16.h>

typedef unsigned int u32;
typedef unsigned short u16;
typedef _Float16 h8 __attribute__((ext_vector_type(8)));
typedef float f4 __attribute__((ext_vector_type(4)));

#define BATCH 2
#define NNODE 768
#define NROWS (BATCH*NNODE)   // 1536
#define CDIM 64
#define ODIM 64
#define EDIM 18
#define E1DIM 32
#define PEDIM 32
#define ADIM 32
#define GDIM 64
#define WCAP 64               // per-wave cap (half-row: mu=19.2 sd=4.3 -> 10+ sigma)

// workspace float offsets
#define OFF_SELF  0
#define OFF_NEIGH (OFF_SELF + NROWS*ODIM)
#define OFF_XAI   (OFF_NEIGH + NROWS*ODIM)
#define OFF_XAJ   (OFF_XAI + NROWS*ADIM)
#define OFF_XG    (OFF_XAJ + NROWS*ADIM)
#define OFF_PKW   (OFF_XG + NROWS*GDIM)    // u32 region

// packed-weight u32 offsets (k-pair-major: pw[kp*N + n] = f16{W[2kp][n], W[2kp+1][n]})
#define PW_WE1 0        // 9*32
#define PW_WE2 288      // 16*32
#define PW_WAE 800      // 16*32
#define PW_WGE 1312     // 16*64
#define PW_WG2 2336     // 32*64
#define PW_TOT 4384
#define PACK_BLOCKS ((PW_TOT + 63)/64)   // 69

__device__ __forceinline__ u32 pk(float a, float b) {
  return __builtin_bit_cast(u32, __builtin_amdgcn_cvt_pkrtz(a, b));
}
__device__ __forceinline__ h8 mk8(u32 a, u32 b, u32 c, u32 d) {
  uint4 v; v.x=a; v.y=b; v.z=c; v.w=d; return __builtin_bit_cast(h8, v);
}
__device__ __forceinline__ f4 splat4(float c) { f4 v; v[0]=c; v[1]=c; v[2]=c; v[3]=c; return v; }
__device__ __forceinline__ float sigm(float v) { return 1.f / (1.f + __expf(-v)); }
#define MFMA(A,B,C) __builtin_amdgcn_mfma_f32_16x16x32_f16(A,B,C,0,0,0)

// ---------------- Kernel A: node projections (fp32) + weight packing ----------------
__global__ __launch_bounds__(64) void node_pre(
    const float* __restrict__ x, const float* __restrict__ Ws, const float* __restrict__ bs,
    const float* __restrict__ Wn, const float* __restrict__ bn,
    const float* __restrict__ Wa1, const float* __restrict__ Wg1,
    const float* __restrict__ We1, const float* __restrict__ We2,
    const float* __restrict__ Wg2, u32* __restrict__ pw,
    float* __restrict__ ws)
{
  const int n = blockIdx.x;
  const int o = threadIdx.x;
  if (n >= NROWS) {
    const int i = (n - NROWS)*64 + o;
    if (i < 288) {
      const int kp = i >> 5, c = i & 31;
      pw[PW_WE1 + i] = pk(We1[(2*kp)*E1DIM + c], We1[(2*kp+1)*E1DIM + c]);
    } else if (i < 800) {
      const int t = i - 288, kp = t >> 5, c = t & 31;
      pw[i] = pk(We2[(2*kp)*PEDIM + c], We2[(2*kp+1)*PEDIM + c]);
    } else if (i < 1312) {
      const int t = i - 800, kp = t >> 5, c = t & 31;
      const float* b = Wa1 + 2*CDIM*ADIM;
      pw[i] = pk(b[(2*kp)*ADIM + c], b[(2*kp+1)*ADIM + c]);
    } else if (i < 2336) {
      const int t = i - 1312, kp = t >> 6, c = t & 63;
      const float* b = Wg1 + CDIM*GDIM;
      pw[i] = pk(b[(2*kp)*GDIM + c], b[(2*kp+1)*GDIM + c]);
    } else if (i < PW_TOT) {
      const int t = i - 2336, kp = t >> 6, c = t & 63;
      pw[i] = pk(Wg2[(2*kp)*ODIM + c], Wg2[(2*kp+1)*ODIM + c]);
    }
    return;
  }
  __shared__ float sx[CDIM];
  sx[o] = x[n*CDIM + o];
  __syncthreads();
  float aS = bs[o], aN = bn[o], aG = 0.f;
  #pragma unroll
  for (int t = 0; t < CDIM; ++t) {
    float xt = sx[t];
    aS += xt * Ws[t*ODIM + o];
    aN += xt * Wn[t*ODIM + o];
    aG += xt * Wg1[t*GDIM + o];
  }
  ws[OFF_SELF  + n*ODIM + o] = aS;
  ws[OFF_NEIGH + n*ODIM + o] = aN;
  ws[OFF_XG    + n*GDIM + o] = aG;
  if (o < ADIM) {
    float aI = 0.f, aJ = 0.f;
    #pragma unroll
    for (int t = 0; t < CDIM; ++t) {
      float xt = sx[t];
      aI += xt * Wa1[t*ADIM + o];
      aJ += xt * Wa1[(CDIM + t)*ADIM + o];
    }
    ws[OFF_XAI + n*ADIM + o] = aI;
    ws[OFF_XAJ + n*ADIM + o] = aJ;
  }
}

// ---------------- Kernel B: MFMA edge pipeline, 2 waves per ROW ----------------
// Block = 128 threads = one row. Wave wv owns adjacency columns [384wv,384wv+384).
// B-fragments built IN-STAGE from L1-hot packed weights; small persistent set.
// launch_bounds(128,4): cap 128 VGPR -> 4 waves/SIMD. If allocator spills
// (WRITE_SIZE blowup) revert to (128,1).
__global__ __launch_bounds__(128, 4) void edge_rows(
    const float* __restrict__ adj, const float* __restrict__ ef,
    const float* __restrict__ be1, const float* __restrict__ be2,
    const float* __restrict__ ba1, const float* __restrict__ Wa2,
    const float* __restrict__ ba2, const float* __restrict__ bg1,
    const float* __restrict__ bg2,
    const float* __restrict__ Wc1, const float* __restrict__ bc1,
    const float* __restrict__ Wc2, const float* __restrict__ bc2,
    const u32* __restrict__ pw, float* __restrict__ ws,
    float* __restrict__ out)
{
  __shared__ _Float16 tbuf[2][32*72];   // 9216 B
  __shared__ float smerge[2][72];       // 576 B
  __shared__ float pbuf[2][64];         // 512 B
  __shared__ float hbuf[64];            // 256 B
  __shared__ u16 slist[2][WCAP];        // 256 B

  const int tid = threadIdx.x, wv = tid >> 6, L = tid & 63;
  const int lo = L & 15, g = L >> 4;
  const int row = blockIdx.x;
  const int jbase = (row >= NNODE) ? NNODE : 0;

  // ---- per-wave ballot compaction over this wave's half of the columns ----
  int cnt = 0;
  const float* arow = adj + (size_t)row * NNODE + 384*wv;
  const unsigned long long lt = (L == 0) ? 0ull : ((~0ull) >> (64 - L));
  for (int jb = 0; jb < 384; jb += 64) {
    const bool act = arow[jb + L] > 0.f;
    const unsigned long long mask = __ballot(act);
    if (act) {
      const int idx = cnt + __popcll(mask & lt);
      if (idx < WCAP) slist[wv][idx] = (u16)(384*wv + jb + L);
    }
    cnt += __popcll(mask);
  }
  const int deg = (cnt < WCAP) ? cnt : WCAP;

  // ---- per-lane bias/constant preloads (small persistent set) ----
  float cbe1[2], cbe2[2], cbah[2], wa2n[2], cbg1[4], cbg2[4];
  #pragma unroll
  for (int nt = 0; nt < 2; ++nt) {
    const int n = nt*16 + lo;
    cbe1[nt] = be1[n];
    cbe2[nt] = be2[n];
    cbah[nt] = ba1[n] + ws[OFF_XAI + (size_t)row*ADIM + n];
    wa2n[nt] = Wa2[n];
  }
  #pragma unroll
  for (int nt = 0; nt < 4; ++nt) {
    const int n = nt*16 + lo;
    cbg1[nt] = bg1[n];
    cbg2[nt] = bg2[n];
  }
  const float ba2v = ba2[0];
  const int k0 = 4*g;

  const float* __restrict__ wxaj = ws + OFF_XAJ;
  const float* __restrict__ wxg  = ws + OFF_XG;
  const float* __restrict__ wnei = ws + OFF_NEIGH;
  const float* efbase = ef + (size_t)row * NNODE * EDIM;
  _Float16* tb = &tbuf[wv][0];
  const u16* sl = slist[wv];

  float acc[4] = {0.f, 0.f, 0.f, 0.f};
  float sw = 0.f;
  const int nbt = (deg + 31) >> 5;

  for (int it = 0; it < nbt; ++it) {
    const int kb = it << 5;
    float wt[2][4];

    // ---- S1: e1 = relu(EF @ We1 + be1) -> tb f16 cols [0,32) ----
    #pragma unroll
    for (int mt = 0; mt < 2; ++mt) {
      const int slotA = kb + mt*16 + lo;
      const int jA = sl[(slotA < deg) ? slotA : 0];
      const float2* efp = (const float2*)(efbase + (size_t)jA * EDIM);
      u32 a0, a1, a2, a3;
      { float2 q = (k0+0 < 9) ? efp[k0+0] : float2{0.f,0.f}; a0 = pk(q.x, q.y); }
      { float2 q = (k0+1 < 9) ? efp[k0+1] : float2{0.f,0.f}; a1 = pk(q.x, q.y); }
      { float2 q = (k0+2 < 9) ? efp[k0+2] : float2{0.f,0.f}; a2 = pk(q.x, q.y); }
      { float2 q = (k0+3 < 9) ? efp[k0+3] : float2{0.f,0.f}; a3 = pk(q.x, q.y); }
      const h8 A = mk8(a0, a1, a2, a3);
      #pragma unroll
      for (int nt = 0; nt < 2; ++nt) {
        const int n = nt*16 + lo;
        const h8 B = mk8((k0+0 < 9) ? pw[PW_WE1 + (k0+0)*32 + n] : 0u,
                         (k0+1 < 9) ? pw[PW_WE1 + (k0+1)*32 + n] : 0u,
                         (k0+2 < 9) ? pw[PW_WE1 + (k0+2)*32 + n] : 0u,
                         (k0+3 < 9) ? pw[PW_WE1 + (k0+3)*32 + n] : 0u);
        f4 d = MFMA(A, B, splat4(cbe1[nt]));
        _Float16* wp = tb + (mt*16 + g*4)*72 + nt*16 + lo;
        wp[0*72] = (_Float16)fmaxf(d[0], 0.f);
        wp[1*72] = (_Float16)fmaxf(d[1], 0.f);
        wp[2*72] = (_Float16)fmaxf(d[2], 0.f);
        wp[3*72] = (_Float16)fmaxf(d[3], 0.f);
      }
    }

    // ---- S2: pe = relu(e1 @ We2 + be2) -> tb f16 cols [32,64) ----
    #pragma unroll
    for (int mt = 0; mt < 2; ++mt) {
      const int e = mt*16 + lo;
      const h8 A = __builtin_bit_cast(h8, *(const uint4*)(tb + e*72 + 8*g));
      #pragma unroll
      for (int nt = 0; nt < 2; ++nt) {
        const int n = nt*16 + lo;
        const h8 B = mk8(pw[PW_WE2 + (k0+0)*32 + n], pw[PW_WE2 + (k0+1)*32 + n],
                         pw[PW_WE2 + (k0+2)*32 + n], pw[PW_WE2 + (k0+3)*32 + n]);
        f4 d = MFMA(A, B, splat4(cbe2[nt]));
        _Float16* wp = tb + (mt*16 + g*4)*72 + 32 + nt*16 + lo;
        wp[0*72] = (_Float16)fmaxf(d[0], 0.f);
        wp[1*72] = (_Float16)fmaxf(d[1], 0.f);
        wp[2*72] = (_Float16)fmaxf(d[2], 0.f);
        wp[3*72] = (_Float16)fmaxf(d[3], 0.f);
      }
    }

    // ---- S3: h/logit + g (shared pe A-frag); g -> tb f16 cols [0,64) ----
    #pragma unroll
    for (int mt = 0; mt < 2; ++mt) {
      const int e = mt*16 + lo;
      const h8 A = __builtin_bit_cast(h8, *(const uint4*)(tb + e*72 + 32 + 8*g));
      int jD[4]; bool vD[4];
      #pragma unroll
      for (int r = 0; r < 4; ++r) {
        const int s = kb + mt*16 + g*4 + r;
        vD[r] = s < deg;
        jD[r] = jbase + sl[vD[r] ? s : 0];
      }
      float lp0 = 0.f, lp1 = 0.f, lp2 = 0.f, lp3 = 0.f;
      #pragma unroll
      for (int nt = 0; nt < 2; ++nt) {
        const int n = nt*16 + lo;
        const h8 B = mk8(pw[PW_WAE + (k0+0)*32 + n], pw[PW_WAE + (k0+1)*32 + n],
                         pw[PW_WAE + (k0+2)*32 + n], pw[PW_WAE + (k0+3)*32 + n]);
        f4 d = MFMA(A, B, splat4(cbah[nt]));
        lp0 += fmaxf(d[0] + wxaj[(size_t)jD[0]*ADIM + n], 0.f) * wa2n[nt];
        lp1 += fmaxf(d[1] + wxaj[(size_t)jD[1]*ADIM + n], 0.f) * wa2n[nt];
        lp2 += fmaxf(d[2] + wxaj[(size_t)jD[2]*ADIM + n], 0.f) * wa2n[nt];
        lp3 += fmaxf(d[3] + wxaj[(size_t)jD[3]*ADIM + n], 0.f) * wa2n[nt];
      }
      lp0 += __shfl_xor(lp0,1); lp0 += __shfl_xor(lp0,2); lp0 += __shfl_xor(lp0,4); lp0 += __shfl_xor(lp0,8);
      lp1 += __shfl_xor(lp1,1); lp1 += __shfl_xor(lp1,2); lp1 += __shfl_xor(lp1,4); lp1 += __shfl_xor(lp1,8);
      lp2 += __shfl_xor(lp2,1); lp2 += __shfl_xor(lp2,2); lp2 += __shfl_xor(lp2,4); lp2 += __shfl_xor(lp2,8);
      lp3 += __shfl_xor(lp3,1); lp3 += __shfl_xor(lp3,2); lp3 += __shfl_xor(lp3,4); lp3 += __shfl_xor(lp3,8);
      wt[mt][0] = vD[0] ? __expf(fminf(lp0 + ba2v, 30.f)) : 0.f;
      wt[mt][1] = vD[1] ? __expf(fminf(lp1 + ba2v, 30.f)) : 0.f;
      wt[mt][2] = vD[2] ? __expf(fminf(lp2 + ba2v, 30.f)) : 0.f;
      wt[mt][3] = vD[3] ? __expf(fminf(lp3 + ba2v, 30.f)) : 0.f;
      sw += wt[mt][0] + wt[mt][1] + wt[mt][2] + wt[mt][3];
      #pragma unroll
      for (int nt = 0; nt < 4; ++nt) {
        const int n = nt*16 + lo;
        const h8 B = mk8(pw[PW_WGE + (k0+0)*64 + n], pw[PW_WGE + (k0+1)*64 + n],
                         pw[PW_WGE + (k0+2)*64 + n], pw[PW_WGE + (k0+3)*64 + n]);
        f4 d = MFMA(A, B, splat4(cbg1[nt]));
        _Float16* wp = tb + (mt*16 + g*4)*72 + n;
        wp[0*72] = (_Float16)fmaxf(d[0] + wxg[(size_t)jD[0]*GDIM + n], 0.f);
        wp[1*72] = (_Float16)fmaxf(d[1] + wxg[(size_t)jD[1]*GDIM + n], 0.f);
        wp[2*72] = (_Float16)fmaxf(d[2] + wxg[(size_t)jD[2]*GDIM + n], 0.f);
        wp[3*72] = (_Float16)fmaxf(d[3] + wxg[(size_t)jD[3]*GDIM + n], 0.f);
      }
    }

    // ---- S4: gates = sigmoid(g @ Wg2 + bg2); acc += w * gate * neigh ----
    #pragma unroll
    for (int mt = 0; mt < 2; ++mt) {
      const int e = mt*16 + lo;
      const h8 Ak0 = __builtin_bit_cast(h8, *(const uint4*)(tb + e*72 + 8*g));
      const h8 Ak1 = __builtin_bit_cast(h8, *(const uint4*)(tb + e*72 + 32 + 8*g));
      int jD[4];
      #pragma unroll
      for (int r = 0; r < 4; ++r) {
        const int s = kb + mt*16 + g*4 + r;
        jD[r] = jbase + sl[(s < deg) ? s : 0];
      }
      #pragma unroll
      for (int nt = 0; nt < 4; ++nt) {
        const int n = nt*16 + lo;
        const h8 B0 = mk8(pw[PW_WG2 + (k0+0)*64 + n], pw[PW_WG2 + (k0+1)*64 + n],
                          pw[PW_WG2 + (k0+2)*64 + n], pw[PW_WG2 + (k0+3)*64 + n]);
        const h8 B1 = mk8(pw[PW_WG2 + (16+k0+0)*64 + n], pw[PW_WG2 + (16+k0+1)*64 + n],
                          pw[PW_WG2 + (16+k0+2)*64 + n], pw[PW_WG2 + (16+k0+3)*64 + n]);
        f4 d = MFMA(Ak0, B0, splat4(cbg2[nt]));
        d = MFMA(Ak1, B1, d);
        acc[nt] += wt[mt][0] * sigm(d[0]) * wnei[(size_t)jD[0]*ODIM + n]
                 + wt[mt][1] * sigm(d[1]) * wnei[(size_t)jD[1]*ODIM + n]
                 + wt[mt][2] * sigm(d[2]) * wnei[(size_t)jD[2]*ODIM + n]
                 + wt[mt][3] * sigm(d[3]) * wnei[(size_t)jD[3]*ODIM + n];
      }
    }
  }

  // ---- per-wave reduce across the 4 lane-groups ----
  sw += __shfl_xor(sw, 16); sw += __shfl_xor(sw, 32);
  #pragma unroll
  for (int nt = 0; nt < 4; ++nt) {
    acc[nt] += __shfl_xor(acc[nt], 16);
    acc[nt] += __shfl_xor(acc[nt], 32);
  }

  // ---- cross-wave merge (pure add: no-max softmax) ----
  if (L == 0) smerge[wv][0] = sw;
  if (g == 0) {
    #pragma unroll
    for (int nt = 0; nt < 4; ++nt) smerge[wv][8 + nt*16 + lo] = acc[nt];
  }
  __syncthreads();
  const float swt = smerge[0][0] + smerge[1][0];
  const float rs = 1.f / fmaxf(swt, 1e-30f);

  // ---- fused output MLP, stage 1 split across waves ----
  float a = 0.f;
  if (wv == 0) {
    const float* selfp = ws + OFF_SELF + (size_t)row * ODIM;
    #pragma unroll 8
    for (int t = 0; t < ODIM; ++t) a += selfp[t] * Wc1[t*ODIM + L];
  } else {
    #pragma unroll 8
    for (int t = 0; t < ODIM; ++t) {
      const float mt_ = (smerge[0][8+t] + smerge[1][8+t]) * rs;
      a += mt_ * Wc1[(ODIM + t)*ODIM + L];
    }
  }
  pbuf[wv][L] = a;
  __syncthreads();

  if (wv == 0) {
    hbuf[L] = fmaxf(pbuf[0][L] + pbuf[1][L] + bc1[L], 0.f);
    float b = bc2[L];
    #pragma unroll 8
    for (int t = 0; t < ODIM; ++t) b += hbuf[t] * Wc2[t*ODIM + L];
    out[(size_t)row*ODIM + L] = b;
  }
}

extern "C" void kernel_launch(void* const* d_in, const int* in_sizes, int n_in,
                              void* d_out, int out_size, void* d_ws, size_t ws_size,
                              hipStream_t stream)
{
  const float* x   = (const float*)d_in[0];
  const float* adj = (const float*)d_in[1];
  const float* ef  = (const float*)d_in[2];
  const float* Ws  = (const float*)d_in[3];
  const float* bs  = (const float*)d_in[4];
  const float* Wn  = (const float*)d_in[5];
  const float* bn  = (const float*)d_in[6];
  const float* We1 = (const float*)d_in[7];
  const float* be1 = (const float*)d_in[8];
  const float* We2 = (const float*)d_in[9];
  const float* be2 = (const float*)d_in[10];
  const float* Wa1 = (const float*)d_in[11];
  const float* ba1 = (const float*)d_in[12];
  const float* Wa2 = (const float*)d_in[13];
  const float* ba2 = (const float*)d_in[14];
  const float* Wg1 = (const float*)d_in[15];
  const float* bg1 = (const float*)d_in[16];
  const float* Wg2 = (const float*)d_in[17];
  const float* bg2 = (const float*)d_in[18];
  const float* Wc1 = (const float*)d_in[19];
  const float* bc1 = (const float*)d_in[20];
  const float* Wc2 = (const float*)d_in[21];
  const float* bc2 = (const float*)d_in[22];
  float* ws  = (float*)d_ws;
  u32* pw = (u32*)(ws + OFF_PKW);
  float* out = (float*)d_out;

  node_pre<<<NROWS + PACK_BLOCKS, 64, 0, stream>>>(x, Ws, bs, Wn, bn, Wa1, Wg1,
                                                   We1, We2, Wg2, pw, ws);
  edge_rows<<<NROWS, 128, 0, stream>>>(adj, ef, be1, be2, ba1, Wa2, ba2, bg1, bg2,
                                       Wc1, bc1, Wc2, bc2, pw, ws, out);
}

// Round 18
// 36.150 us; speedup vs baseline: 2.0683x; 2.0683x over previous
//
#include <hip/hip_runtime.h>
#include <hip/hip_bf16.h>

typedef unsigned int u32;
typedef unsigned short u16;
typedef _Float16 h8 __attribute__((ext_vector_type(8)));
typedef float f4 __attribute__((ext_vector_type(4)));

#define BATCH 2
#define NNODE 768
#define NROWS (BATCH*NNODE)   // 1536
#define CDIM 64
#define ODIM 64
#define EDIM 18
#define E1DIM 32
#define PEDIM 32
#define ADIM 32
#define GDIM 64
#define WCAP 64               // per-wave cap (half-row: mu=19.2 sd=4.3 -> 10+ sigma)

// workspace float offsets
#define OFF_SELF  0
#define OFF_NEIGH (OFF_SELF + NROWS*ODIM)
#define OFF_XAI   (OFF_NEIGH + NROWS*ODIM)
#define OFF_XAJ   (OFF_XAI + NROWS*ADIM)
#define OFF_XG    (OFF_XAJ + NROWS*ADIM)
#define OFF_PKW   (OFF_XG + NROWS*GDIM)    // u32 region

// packed-weight u32 offsets (k-pair-major: pw[kp*N + n] = f16{W[2kp][n], W[2kp+1][n]})
#define PW_WE1 0        // 9*32
#define PW_WE2 288      // 16*32
#define PW_WAE 800      // 16*32
#define PW_WGE 1312     // 16*64
#define PW_WG2 2336     // 32*64
#define PW_TOT 4384
#define PACK_BLOCKS ((PW_TOT + 63)/64)   // 69

__device__ __forceinline__ u32 pk(float a, float b) {
  return __builtin_bit_cast(u32, __builtin_amdgcn_cvt_pkrtz(a, b));
}
__device__ __forceinline__ h8 mk8(u32 a, u32 b, u32 c, u32 d) {
  uint4 v; v.x=a; v.y=b; v.z=c; v.w=d; return __builtin_bit_cast(h8, v);
}
__device__ __forceinline__ f4 splat4(float c) { f4 v; v[0]=c; v[1]=c; v[2]=c; v[3]=c; return v; }
__device__ __forceinline__ float sigm(float v) { return 1.f / (1.f + __expf(-v)); }
#define MFMA(A,B,C) __builtin_amdgcn_mfma_f32_16x16x32_f16(A,B,C,0,0,0)

// ---------------- Kernel A: node projections (fp32) + weight packing ----------------
__global__ __launch_bounds__(64) void node_pre(
    const float* __restrict__ x, const float* __restrict__ Ws, const float* __restrict__ bs,
    const float* __restrict__ Wn, const float* __restrict__ bn,
    const float* __restrict__ Wa1, const float* __restrict__ Wg1,
    const float* __restrict__ We1, const float* __restrict__ We2,
    const float* __restrict__ Wg2, u32* __restrict__ pw,
    float* __restrict__ ws)
{
  const int n = blockIdx.x;
  const int o = threadIdx.x;
  if (n >= NROWS) {
    const int i = (n - NROWS)*64 + o;
    if (i < 288) {
      const int kp = i >> 5, c = i & 31;
      pw[PW_WE1 + i] = pk(We1[(2*kp)*E1DIM + c], We1[(2*kp+1)*E1DIM + c]);
    } else if (i < 800) {
      const int t = i - 288, kp = t >> 5, c = t & 31;
      pw[i] = pk(We2[(2*kp)*PEDIM + c], We2[(2*kp+1)*PEDIM + c]);
    } else if (i < 1312) {
      const int t = i - 800, kp = t >> 5, c = t & 31;
      const float* b = Wa1 + 2*CDIM*ADIM;
      pw[i] = pk(b[(2*kp)*ADIM + c], b[(2*kp+1)*ADIM + c]);
    } else if (i < 2336) {
      const int t = i - 1312, kp = t >> 6, c = t & 63;
      const float* b = Wg1 + CDIM*GDIM;
      pw[i] = pk(b[(2*kp)*GDIM + c], b[(2*kp+1)*GDIM + c]);
    } else if (i < PW_TOT) {
      const int t = i - 2336, kp = t >> 6, c = t & 63;
      pw[i] = pk(Wg2[(2*kp)*ODIM + c], Wg2[(2*kp+1)*ODIM + c]);
    }
    return;
  }
  __shared__ float sx[CDIM];
  sx[o] = x[n*CDIM + o];
  __syncthreads();
  float aS = bs[o], aN = bn[o], aG = 0.f;
  #pragma unroll
  for (int t = 0; t < CDIM; ++t) {
    float xt = sx[t];
    aS += xt * Ws[t*ODIM + o];
    aN += xt * Wn[t*ODIM + o];
    aG += xt * Wg1[t*GDIM + o];
  }
  ws[OFF_SELF  + n*ODIM + o] = aS;
  ws[OFF_NEIGH + n*ODIM + o] = aN;
  ws[OFF_XG    + n*GDIM + o] = aG;
  if (o < ADIM) {
    float aI = 0.f, aJ = 0.f;
    #pragma unroll
    for (int t = 0; t < CDIM; ++t) {
      float xt = sx[t];
      aI += xt * Wa1[t*ADIM + o];
      aJ += xt * Wa1[(CDIM + t)*ADIM + o];
    }
    ws[OFF_XAI + n*ADIM + o] = aI;
    ws[OFF_XAJ + n*ADIM + o] = aJ;
  }
}

// ---------------- Kernel B: MFMA edge pipeline, 2 waves per ROW ----------------
// Block = 128 threads = one row. Wave wv compacts+processes adjacency columns
// [384wv, 384wv+384) as its own edge list (M=32 tiles, mt in {0,1}).
// No-max softmax => cross-wave merge is a pure (sw, acc) add via LDS.
// Fused output MLP tail: stage1 split across waves, stage2 on wave0.
// launch_bounds(128,1): allocator free (~160 VGPR, 3 waves/SIMD) -- any tighter
// bound snaps to 64 VGPR and spills catastrophically (measured r9, r17).
__global__ __launch_bounds__(128, 1) void edge_rows(
    const float* __restrict__ adj, const float* __restrict__ ef,
    const float* __restrict__ be1, const float* __restrict__ be2,
    const float* __restrict__ ba1, const float* __restrict__ Wa2,
    const float* __restrict__ ba2, const float* __restrict__ bg1,
    const float* __restrict__ bg2,
    const float* __restrict__ Wc1, const float* __restrict__ bc1,
    const float* __restrict__ Wc2, const float* __restrict__ bc2,
    const u32* __restrict__ pw, float* __restrict__ ws,
    float* __restrict__ out)
{
  __shared__ _Float16 tbuf[2][32*72];   // 9216 B
  __shared__ float smerge[2][72];       // 576 B
  __shared__ float pbuf[2][64];         // 512 B
  __shared__ float hbuf[64];            // 256 B
  __shared__ u16 slist[2][WCAP];        // 256 B

  const int tid = threadIdx.x, wv = tid >> 6, L = tid & 63;
  const int lo = L & 15, g = L >> 4;
  const int row = blockIdx.x;
  const int jbase = (row >= NNODE) ? NNODE : 0;

  // ---- per-wave ballot compaction over this wave's half of the columns ----
  int cnt = 0;
  const float* arow = adj + (size_t)row * NNODE + 384*wv;
  const unsigned long long lt = (L == 0) ? 0ull : ((~0ull) >> (64 - L));
  for (int jb = 0; jb < 384; jb += 64) {
    const bool act = arow[jb + L] > 0.f;
    const unsigned long long mask = __ballot(act);
    if (act) {
      const int idx = cnt + __popcll(mask & lt);
      if (idx < WCAP) slist[wv][idx] = (u16)(384*wv + jb + L);
    }
    cnt += __popcll(mask);
  }
  const int deg = (cnt < WCAP) ? cnt : WCAP;

  // ---- preload B-fragments (row-invariant, held in VGPRs) ----
  h8 Bwe1[2], Bwe2[2], Bwae[2], Bwge[4], Bwg2a[4], Bwg2b[4];
  #pragma unroll
  for (int nt = 0; nt < 2; ++nt) {
    const int n = nt*16 + lo;
    const int k0 = 4*g;
    u32 w0 = (k0+0 < 9) ? pw[PW_WE1 + (k0+0)*32 + n] : 0u;
    u32 w1 = (k0+1 < 9) ? pw[PW_WE1 + (k0+1)*32 + n] : 0u;
    u32 w2 = (k0+2 < 9) ? pw[PW_WE1 + (k0+2)*32 + n] : 0u;
    u32 w3 = (k0+3 < 9) ? pw[PW_WE1 + (k0+3)*32 + n] : 0u;
    Bwe1[nt] = mk8(w0, w1, w2, w3);
    Bwe2[nt] = mk8(pw[PW_WE2 + (k0+0)*32 + n], pw[PW_WE2 + (k0+1)*32 + n],
                   pw[PW_WE2 + (k0+2)*32 + n], pw[PW_WE2 + (k0+3)*32 + n]);
    Bwae[nt] = mk8(pw[PW_WAE + (k0+0)*32 + n], pw[PW_WAE + (k0+1)*32 + n],
                   pw[PW_WAE + (k0+2)*32 + n], pw[PW_WAE + (k0+3)*32 + n]);
  }
  #pragma unroll
  for (int nt = 0; nt < 4; ++nt) {
    const int n = nt*16 + lo;
    const int k0 = 4*g;
    Bwge[nt]  = mk8(pw[PW_WGE + (k0+0)*64 + n], pw[PW_WGE + (k0+1)*64 + n],
                    pw[PW_WGE + (k0+2)*64 + n], pw[PW_WGE + (k0+3)*64 + n]);
    Bwg2a[nt] = mk8(pw[PW_WG2 + (k0+0)*64 + n], pw[PW_WG2 + (k0+1)*64 + n],
                    pw[PW_WG2 + (k0+2)*64 + n], pw[PW_WG2 + (k0+3)*64 + n]);
    Bwg2b[nt] = mk8(pw[PW_WG2 + (16+k0+0)*64 + n], pw[PW_WG2 + (16+k0+1)*64 + n],
                    pw[PW_WG2 + (16+k0+2)*64 + n], pw[PW_WG2 + (16+k0+3)*64 + n]);
  }

  // ---- per-lane bias/constant preloads ----
  float cbe1[2], cbe2[2], cbah[2], wa2n[2], cbg1[4], cbg2[4];
  #pragma unroll
  for (int nt = 0; nt < 2; ++nt) {
    const int n = nt*16 + lo;
    cbe1[nt] = be1[n];
    cbe2[nt] = be2[n];
    cbah[nt] = ba1[n] + ws[OFF_XAI + (size_t)row*ADIM + n];
    wa2n[nt] = Wa2[n];
  }
  #pragma unroll
  for (int nt = 0; nt < 4; ++nt) {
    const int n = nt*16 + lo;
    cbg1[nt] = bg1[n];
    cbg2[nt] = bg2[n];
  }
  const float ba2v = ba2[0];

  const float* __restrict__ wxaj = ws + OFF_XAJ;
  const float* __restrict__ wxg  = ws + OFF_XG;
  const float* __restrict__ wnei = ws + OFF_NEIGH;
  const float* efbase = ef + (size_t)row * NNODE * EDIM;
  _Float16* tb = &tbuf[wv][0];
  const u16* sl = slist[wv];

  float acc[4] = {0.f, 0.f, 0.f, 0.f};
  float sw = 0.f;
  const int nbt = (deg + 31) >> 5;

  for (int it = 0; it < nbt; ++it) {
    const int kb = it << 5;
    float wt[2][4];

    // ---- S1: e1 = relu(EF @ We1 + be1) -> tb f16 cols [0,32) ----
    #pragma unroll
    for (int mt = 0; mt < 2; ++mt) {
      const int slotA = kb + mt*16 + lo;
      const int jA = sl[(slotA < deg) ? slotA : 0];
      const float2* efp = (const float2*)(efbase + (size_t)jA * EDIM);
      u32 a0, a1, a2, a3;
      const int k0 = 4*g;
      { float2 q = (k0+0 < 9) ? efp[k0+0] : float2{0.f,0.f}; a0 = pk(q.x, q.y); }
      { float2 q = (k0+1 < 9) ? efp[k0+1] : float2{0.f,0.f}; a1 = pk(q.x, q.y); }
      { float2 q = (k0+2 < 9) ? efp[k0+2] : float2{0.f,0.f}; a2 = pk(q.x, q.y); }
      { float2 q = (k0+3 < 9) ? efp[k0+3] : float2{0.f,0.f}; a3 = pk(q.x, q.y); }
      const h8 A = mk8(a0, a1, a2, a3);
      #pragma unroll
      for (int nt = 0; nt < 2; ++nt) {
        f4 d = MFMA(A, Bwe1[nt], splat4(cbe1[nt]));
        _Float16* wp = tb + (mt*16 + g*4)*72 + nt*16 + lo;
        wp[0*72] = (_Float16)fmaxf(d[0], 0.f);
        wp[1*72] = (_Float16)fmaxf(d[1], 0.f);
        wp[2*72] = (_Float16)fmaxf(d[2], 0.f);
        wp[3*72] = (_Float16)fmaxf(d[3], 0.f);
      }
    }

    // ---- S2: pe = relu(e1 @ We2 + be2) -> tb f16 cols [32,64) ----
    #pragma unroll
    for (int mt = 0; mt < 2; ++mt) {
      const int e = mt*16 + lo;
      const h8 A = __builtin_bit_cast(h8, *(const uint4*)(tb + e*72 + 8*g));
      #pragma unroll
      for (int nt = 0; nt < 2; ++nt) {
        f4 d = MFMA(A, Bwe2[nt], splat4(cbe2[nt]));
        _Float16* wp = tb + (mt*16 + g*4)*72 + 32 + nt*16 + lo;
        wp[0*72] = (_Float16)fmaxf(d[0], 0.f);
        wp[1*72] = (_Float16)fmaxf(d[1], 0.f);
        wp[2*72] = (_Float16)fmaxf(d[2], 0.f);
        wp[3*72] = (_Float16)fmaxf(d[3], 0.f);
      }
    }

    // ---- S3: h/logit + g (shared pe A-frag); g -> tb f16 cols [0,64) ----
    #pragma unroll
    for (int mt = 0; mt < 2; ++mt) {
      const int e = mt*16 + lo;
      const h8 A = __builtin_bit_cast(h8, *(const uint4*)(tb + e*72 + 32 + 8*g));
      int jD[4]; bool vD[4];
      #pragma unroll
      for (int r = 0; r < 4; ++r) {
        const int s = kb + mt*16 + g*4 + r;
        vD[r] = s < deg;
        jD[r] = jbase + sl[vD[r] ? s : 0];
      }
      float lp0 = 0.f, lp1 = 0.f, lp2 = 0.f, lp3 = 0.f;
      #pragma unroll
      for (int nt = 0; nt < 2; ++nt) {
        f4 d = MFMA(A, Bwae[nt], splat4(cbah[nt]));
        const int n = nt*16 + lo;
        lp0 += fmaxf(d[0] + wxaj[(size_t)jD[0]*ADIM + n], 0.f) * wa2n[nt];
        lp1 += fmaxf(d[1] + wxaj[(size_t)jD[1]*ADIM + n], 0.f) * wa2n[nt];
        lp2 += fmaxf(d[2] + wxaj[(size_t)jD[2]*ADIM + n], 0.f) * wa2n[nt];
        lp3 += fmaxf(d[3] + wxaj[(size_t)jD[3]*ADIM + n], 0.f) * wa2n[nt];
      }
      lp0 += __shfl_xor(lp0,1); lp0 += __shfl_xor(lp0,2); lp0 += __shfl_xor(lp0,4); lp0 += __shfl_xor(lp0,8);
      lp1 += __shfl_xor(lp1,1); lp1 += __shfl_xor(lp1,2); lp1 += __shfl_xor(lp1,4); lp1 += __shfl_xor(lp1,8);
      lp2 += __shfl_xor(lp2,1); lp2 += __shfl_xor(lp2,2); lp2 += __shfl_xor(lp2,4); lp2 += __shfl_xor(lp2,8);
      lp3 += __shfl_xor(lp3,1); lp3 += __shfl_xor(lp3,2); lp3 += __shfl_xor(lp3,4); lp3 += __shfl_xor(lp3,8);
      wt[mt][0] = vD[0] ? __expf(fminf(lp0 + ba2v, 30.f)) : 0.f;
      wt[mt][1] = vD[1] ? __expf(fminf(lp1 + ba2v, 30.f)) : 0.f;
      wt[mt][2] = vD[2] ? __expf(fminf(lp2 + ba2v, 30.f)) : 0.f;
      wt[mt][3] = vD[3] ? __expf(fminf(lp3 + ba2v, 30.f)) : 0.f;
      sw += wt[mt][0] + wt[mt][1] + wt[mt][2] + wt[mt][3];
      #pragma unroll
      for (int nt = 0; nt < 4; ++nt) {
        f4 d = MFMA(A, Bwge[nt], splat4(cbg1[nt]));
        const int n = nt*16 + lo;
        _Float16* wp = tb + (mt*16 + g*4)*72 + n;
        wp[0*72] = (_Float16)fmaxf(d[0] + wxg[(size_t)jD[0]*GDIM + n], 0.f);
        wp[1*72] = (_Float16)fmaxf(d[1] + wxg[(size_t)jD[1]*GDIM + n], 0.f);
        wp[2*72] = (_Float16)fmaxf(d[2] + wxg[(size_t)jD[2]*GDIM + n], 0.f);
        wp[3*72] = (_Float16)fmaxf(d[3] + wxg[(size_t)jD[3]*GDIM + n], 0.f);
      }
    }

    // ---- S4: gates = sigmoid(g @ Wg2 + bg2); acc += w * gate * neigh ----
    #pragma unroll
    for (int mt = 0; mt < 2; ++mt) {
      const int e = mt*16 + lo;
      const h8 Ak0 = __builtin_bit_cast(h8, *(const uint4*)(tb + e*72 + 8*g));
      const h8 Ak1 = __builtin_bit_cast(h8, *(const uint4*)(tb + e*72 + 32 + 8*g));
      int jD[4];
      #pragma unroll
      for (int r = 0; r < 4; ++r) {
        const int s = kb + mt*16 + g*4 + r;
        jD[r] = jbase + sl[(s < deg) ? s : 0];
      }
      #pragma unroll
      for (int nt = 0; nt < 4; ++nt) {
        f4 d = MFMA(Ak0, Bwg2a[nt], splat4(cbg2[nt]));
        d = MFMA(Ak1, Bwg2b[nt], d);
        const int n = nt*16 + lo;
        acc[nt] += wt[mt][0] * sigm(d[0]) * wnei[(size_t)jD[0]*ODIM + n]
                 + wt[mt][1] * sigm(d[1]) * wnei[(size_t)jD[1]*ODIM + n]
                 + wt[mt][2] * sigm(d[2]) * wnei[(size_t)jD[2]*ODIM + n]
                 + wt[mt][3] * sigm(d[3]) * wnei[(size_t)jD[3]*ODIM + n];
      }
    }
  }

  // ---- per-wave reduce across the 4 lane-groups ----
  sw += __shfl_xor(sw, 16); sw += __shfl_xor(sw, 32);
  #pragma unroll
  for (int nt = 0; nt < 4; ++nt) {
    acc[nt] += __shfl_xor(acc[nt], 16);
    acc[nt] += __shfl_xor(acc[nt], 32);
  }

  // ---- cross-wave merge (pure add: no-max softmax) ----
  if (L == 0) smerge[wv][0] = sw;
  if (g == 0) {
    #pragma unroll
    for (int nt = 0; nt < 4; ++nt) smerge[wv][8 + nt*16 + lo] = acc[nt];
  }
  __syncthreads();
  const float swt = smerge[0][0] + smerge[1][0];
  const float rs = 1.f / fmaxf(swt, 1e-30f);

  // ---- fused output MLP, stage 1 split across waves ----
  // wave0: self-half of Wc1; wave1: msg-half.
  float a = 0.f;
  if (wv == 0) {
    const float* selfp = ws + OFF_SELF + (size_t)row * ODIM;
    #pragma unroll 8
    for (int t = 0; t < ODIM; ++t) a += selfp[t] * Wc1[t*ODIM + L];
  } else {
    #pragma unroll 8
    for (int t = 0; t < ODIM; ++t) {
      const float mt_ = (smerge[0][8+t] + smerge[1][8+t]) * rs;
      a += mt_ * Wc1[(ODIM + t)*ODIM + L];
    }
  }
  pbuf[wv][L] = a;
  __syncthreads();

  if (wv == 0) {
    hbuf[L] = fmaxf(pbuf[0][L] + pbuf[1][L] + bc1[L], 0.f);
    float b = bc2[L];
    #pragma unroll 8
    for (int t = 0; t < ODIM; ++t) b += hbuf[t] * Wc2[t*ODIM + L];
    out[(size_t)row*ODIM + L] = b;
  }
}

extern "C" void kernel_launch(void* const* d_in, const int* in_sizes, int n_in,
                              void* d_out, int out_size, void* d_ws, size_t ws_size,
                              hipStream_t stream)
{
  const float* x   = (const float*)d_in[0];
  const float* adj = (const float*)d_in[1];
  const float* ef  = (const float*)d_in[2];
  const float* Ws  = (const float*)d_in[3];
  const float* bs  = (const float*)d_in[4];
  const float* Wn  = (const float*)d_in[5];
  const float* bn  = (const float*)d_in[6];
  const float* We1 = (const float*)d_in[7];
  const float* be1 = (const float*)d_in[8];
  const float* We2 = (const float*)d_in[9];
  const float* be2 = (const float*)d_in[10];
  const float* Wa1 = (const float*)d_in[11];
  const float* ba1 = (const float*)d_in[12];
  const float* Wa2 = (const float*)d_in[13];
  const float* ba2 = (const float*)d_in[14];
  const float* Wg1 = (const float*)d_in[15];
  const float* bg1 = (const float*)d_in[16];
  const float* Wg2 = (const float*)d_in[17];
  const float* bg2 = (const float*)d_in[18];
  const float* Wc1 = (const float*)d_in[19];
  const float* bc1 = (const float*)d_in[20];
  const float* Wc2 = (const float*)d_in[21];
  const float* bc2 = (const float*)d_in[22];
  float* ws  = (float*)d_ws;
  u32* pw = (u32*)(ws + OFF_PKW);
  float* out = (float*)d_out;

  node_pre<<<NROWS + PACK_BLOCKS, 64, 0, stream>>>(x, Ws, bs, Wn, bn, Wa1, Wg1,
                                                   We1, We2, Wg2, pw, ws);
  edge_rows<<<NROWS, 128, 0, stream>>>(adj, ef, be1, be2, ba1, Wa2, ba2, bg1, bg2,
                                       Wc1, bc1, Wc2, bc2, pw, ws, out);
}